// Round 11
// baseline (218.076 us; speedup 1.0000x reference)
//
#include <hip/hip_runtime.h>
#include <hip/hip_bf16.h>
#include <math.h>

// ---------------------------------------------------------------------------
// VQ quantizer + 6-layer ReLU MLP via split-bf16 MFMA.
//   f32 GEMM ~= Ah*Bh + Ah*Bl + Al*Bh  (drop lo*lo ~2^-16 rel)
//   R11: R10 base (212.2us) + quantize E=4 elems/lane with EXPLICIT
//        double-buffered LDS prefetch (DS-pipe-bound fix: DS insts halve;
//        k+1 loads issued before k's 32-FMA block so DS || VALU overlap).
// Workspace map (40MB):
//   [0..16M)  phase1: qhi@0(1M), wihi@1M, wilo@3M   (dead after L1)
//             phase2: mid partial p0@0(8M), p1@8M
//             phase3: wohi@0(2M), wolo@2M
//   [16..24M) h planes: hhi@16M, hlo@20M
//   [24..40M) whhi@24M, whlo@32M (dead after mids) -> phase3: l6par@24M(16M)
// ---------------------------------------------------------------------------

#define B_ROWS 1024
#define D_IN   512
#define HDIM   2048
#define NTOT   (B_ROWS * D_IN)
#define NCODE  256
#define EDIM   8

typedef __attribute__((ext_vector_type(8))) short bf16x8;
typedef __attribute__((ext_vector_type(4))) float f32x4;

__device__ inline void gload_lds16(const void* g, void* l) {
    __builtin_amdgcn_global_load_lds(
        (const __attribute__((address_space(1))) void*)g,
        (__attribute__((address_space(3))) void*)l, 16, 0, 0);
}

__device__ inline ushort bf16_hi_bits(float v, float* hi_f) {
    __hip_bfloat16 h = __float2bfloat16(v);
    *hi_f = __bfloat162float(h);
    ushort u; __builtin_memcpy(&u, &h, 2); return u;
}
__device__ inline ushort bf16_bits(float v) {
    __hip_bfloat16 h = __float2bfloat16(v);
    ushort u; __builtin_memcpy(&u, &h, 2); return u;
}

// ---------------- fused: quantize (blocks 0..511) + wi/wh split --------------
// Quantize: 4 elems/lane, explicit LDS->reg double-buffer prefetch.
// Per-k distance bits identical to R5/R10: d = RN(RN(sm+E[k]) - dot2),
// dot2 = sequential FMA of p2*w, p2 = 2*p (exact pow2 fold).
__global__ __launch_bounds__(256) void fused_pre(
    const float* __restrict__ x, const float* __restrict__ embW,
    const float* __restrict__ Wi, const float* __restrict__ Wh,
    ushort* __restrict__ qhi,
    ushort* __restrict__ wihi, ushort* __restrict__ wilo,
    ushort* __restrict__ whhi, ushort* __restrict__ whlo,
    float* __restrict__ loss_out)
{
    __shared__ float sWE[NCODE][12];   // w0..w7, E, pad -> 48B rows
    const int tid = threadIdx.x;

    if (blockIdx.x >= 512) {
        // ---- weight split: 1280 blocks x 256 thr x 4 float4 ----
        const int sidx = blockIdx.x - 512;
        #pragma unroll
        for (int s = 0; s < 4; ++s) {
            const int g = sidx * 1024 + s * 256 + tid;   // < 1310720
            const float* src; ushort* hi; ushort* lo; int j;
            if (g < 262144) { src = Wi; hi = wihi; lo = wilo; j = g; }
            else            { src = Wh; hi = whhi; lo = whlo; j = g - 262144; }
            float4 v = reinterpret_cast<const float4*>(src)[j];
            float f[4] = {v.x, v.y, v.z, v.w};
            ushort hh[4], ll[4];
            #pragma unroll
            for (int c = 0; c < 4; ++c) {
                float hf;
                hh[c] = bf16_hi_bits(f[c], &hf);
                ll[c] = bf16_bits(f[c] - hf);
            }
            ushort4 h4 = {hh[0], hh[1], hh[2], hh[3]};
            ushort4 l4 = {ll[0], ll[1], ll[2], ll[3]};
            reinterpret_cast<ushort4*>(hi)[j] = h4;
            reinterpret_cast<ushort4*>(lo)[j] = l4;
        }
        return;
    }

    // ---- quantize part ----
    {   // thread k: codebook row + E (numpy pairwise order)
        const float4 a4 = *reinterpret_cast<const float4*>(&embW[tid * EDIM]);
        const float4 b4 = *reinterpret_cast<const float4*>(&embW[tid * EDIM + 4]);
        float s0 = __fmul_rn(a4.x, a4.x), s1 = __fmul_rn(a4.y, a4.y);
        float s2 = __fmul_rn(a4.z, a4.z), s3 = __fmul_rn(a4.w, a4.w);
        float s4 = __fmul_rn(b4.x, b4.x), s5 = __fmul_rn(b4.y, b4.y);
        float s6 = __fmul_rn(b4.z, b4.z), s7 = __fmul_rn(b4.w, b4.w);
        float a = __fadd_rn(__fadd_rn(s0, s1), __fadd_rn(s2, s3));
        float b = __fadd_rn(__fadd_rn(s4, s5), __fadd_rn(s6, s7));
        sWE[tid][0] = a4.x; sWE[tid][1] = a4.y; sWE[tid][2] = a4.z; sWE[tid][3] = a4.w;
        sWE[tid][4] = b4.x; sWE[tid][5] = b4.y; sWE[tid][6] = b4.z; sWE[tid][7] = b4.w;
        sWE[tid][8] = __fadd_rn(a, b);
    }
    __syncthreads();

    const int nbase = blockIdx.x * 1024 + tid;     // elems nbase + j*256, j<4

    float p2[4][EDIM], sm[4];
    #pragma unroll
    for (int j = 0; j < 4; ++j) {
        const float v = x[nbase + j * 256];
        float p[EDIM];
        #pragma unroll
        for (int e = 0; e < EDIM; ++e)
            p[e] = powf(v, (float)(e + 1));        // match np.power f32
        float a = __fadd_rn(__fadd_rn(p[0], p[1]), __fadd_rn(p[2], p[3]));
        float b = __fadd_rn(__fadd_rn(p[4], p[5]), __fadd_rn(p[6], p[7]));
        sm[j] = __fadd_rn(a, b);
        #pragma unroll
        for (int e = 0; e < EDIM; ++e)
            p2[j][e] = 2.0f * p[e];                // exact
    }

    float best[4] = {INFINITY, INFINITY, INFINITY, INFINITY};
    int   bi[4]   = {0, 0, 0, 0};

    // explicit double-buffer: prefetch k+1's row while computing k
    float4 w0a = *reinterpret_cast<const float4*>(&sWE[0][0]);
    float4 w1a = *reinterpret_cast<const float4*>(&sWE[0][4]);
    float  Ea  = sWE[0][8];

    #pragma unroll 2
    for (int k = 0; k < NCODE; ++k) {
        const int kn = (k + 1) & (NCODE - 1);
        // issue next-code loads FIRST (no dep on them below until rotate)
        float4 w0b = *reinterpret_cast<const float4*>(&sWE[kn][0]);
        float4 w1b = *reinterpret_cast<const float4*>(&sWE[kn][4]);
        float  Eb  = sWE[kn][8];

        // 4 independent chains cover the DS latency
        #pragma unroll
        for (int j = 0; j < 4; ++j) {
            float dot = 0.f;
            dot = fmaf(p2[j][0], w0a.x, dot); dot = fmaf(p2[j][1], w0a.y, dot);
            dot = fmaf(p2[j][2], w0a.z, dot); dot = fmaf(p2[j][3], w0a.w, dot);
            dot = fmaf(p2[j][4], w1a.x, dot); dot = fmaf(p2[j][5], w1a.y, dot);
            dot = fmaf(p2[j][6], w1a.z, dot); dot = fmaf(p2[j][7], w1a.w, dot);
            float d = __fsub_rn(__fadd_rn(sm[j], Ea), dot);
            if (d < best[j]) { best[j] = d; bi[j] = k; }   // first-index-wins
        }
        w0a = w0b; w1a = w1b; Ea = Eb;
    }

    #pragma unroll
    for (int j = 0; j < 4; ++j) {
        const int n  = nbase + j * 256;
        const int bo = n & (B_ROWS - 1);
        const int dd = n >> 10;
        qhi[bo * D_IN + dd] = bf16_bits((float)bi[j]);     // 0..255 exact bf16
    }
    if (blockIdx.x == 0 && tid == 0) loss_out[0] = 0.0f;
}

// ---------------- wo split (after mids; writes into freed phase-3 region) ----
__global__ __launch_bounds__(256) void wo_split(
    const float* __restrict__ Wo, ushort* __restrict__ hi, ushort* __restrict__ lo)
{
    const int tid = threadIdx.x;
    #pragma unroll
    for (int s = 0; s < 4; ++s) {
        const int j = blockIdx.x * 1024 + s * 256 + tid;   // < 262144
        float4 v = reinterpret_cast<const float4*>(Wo)[j];
        float f[4] = {v.x, v.y, v.z, v.w};
        ushort hh[4], ll[4];
        #pragma unroll
        for (int c = 0; c < 4; ++c) {
            float hf;
            hh[c] = bf16_hi_bits(f[c], &hf);
            ll[c] = bf16_bits(f[c] - hf);
        }
        ushort4 h4 = {hh[0], hh[1], hh[2], hh[3]};
        ushort4 l4 = {ll[0], ll[1], ll[2], ll[3]};
        reinterpret_cast<ushort4*>(hi)[j] = h4;
        reinterpret_cast<ushort4*>(lo)[j] = l4;
    }
}

// ---------------- L1 GEMM (R3-proven): block 64x128, wave 32x64, BK=64 -------
template<bool ALO, bool PARTIAL>
__global__ __launch_bounds__(256) void gemm_split(
    const ushort* __restrict__ Ahi, const ushort* __restrict__ Alo,
    const ushort* __restrict__ Whi, const ushort* __restrict__ Wlo,
    const float* __restrict__ bias,
    ushort* __restrict__ Ohi, ushort* __restrict__ Olo,
    float* __restrict__ OF, int N, int K, int klen)
{
    constexpr int BUF = 49152;
    constexpr int OFF_AH = 0, OFF_AL = 8192, OFF_BH = 16384;
    __shared__ char lds[2 * BUF];

    const int tid = threadIdx.x, lane = tid & 63, wid = tid >> 6;

    const int gy = gridDim.y;
    const int nwg = gridDim.x * gy;
    int lin = blockIdx.x * gy + blockIdx.y;
    int q   = nwg >> 3;
    int sw  = (lin & 7) * q + (lin >> 3);
    int bx  = sw / gy, by2 = sw % gy;
    const int bm   = (by2 & 15) << 6;
    const int kz   = by2 >> 4;
    const int kbeg = kz * klen;
    const int bn   = bx << 7;

    const int wm = (wid >> 1) << 5;
    const int wn = (wid & 1) << 6;

    constexpr int NSEGW = ALO ? 12 : 10;
    const ushort* gp[NSEGW];
    uint ldsoff[NSEGW];
    #pragma unroll
    for (int i = 0; i < NSEGW; ++i) {
        int s = wid + i * 4;
        const ushort* pl; int row0, base, sip;
        if (ALO) {
            if (s < 8)       { pl = Ahi; row0 = bm; base = OFF_AH;         sip = s; }
            else if (s < 16) { pl = Alo; row0 = bm; base = OFF_AL;         sip = s - 8; }
            else if (s < 32) { pl = Whi; row0 = bn; base = OFF_BH;         sip = s - 16; }
            else             { pl = Wlo; row0 = bn; base = OFF_BH + 16384; sip = s - 32; }
        } else {
            if (s < 8)       { pl = Ahi; row0 = bm; base = OFF_AH;         sip = s; }
            else if (s < 24) { pl = Whi; row0 = bn; base = OFF_BH;         sip = s - 8; }
            else             { pl = Wlo; row0 = bn; base = OFF_BH + 16384; sip = s - 24; }
        }
        int r  = sip * 8 + (lane >> 3);
        int ch = (lane & 7) ^ (r & 7);
        gp[i]     = pl + (size_t)(row0 + r) * K + kbeg + ch * 8;
        ldsoff[i] = base + sip * 1024;
    }

    uint aoff[2][2], boff[4][2];
    #pragma unroll
    for (int f = 0; f < 2; ++f) {
        int ar = wm + f * 16 + (lane & 15);
        #pragma unroll
        for (int s = 0; s < 2; ++s) {
            int ch = (s * 4 + (lane >> 4)) ^ (ar & 7);
            aoff[f][s] = OFF_AH + ar * 128 + ch * 16;
        }
    }
    #pragma unroll
    for (int f = 0; f < 4; ++f) {
        int br = wn + f * 16 + (lane & 15);
        #pragma unroll
        for (int s = 0; s < 2; ++s) {
            int ch = (s * 4 + (lane >> 4)) ^ (br & 7);
            boff[f][s] = OFF_BH + br * 128 + ch * 16;
        }
    }

    auto stage = [&](int kt, int b) {
        #pragma unroll
        for (int i = 0; i < NSEGW; ++i)
            gload_lds16(gp[i] + kt * 64, lds + b * BUF + ldsoff[i]);
    };

    f32x4 acc[2][4] = {};
    const int NT = klen >> 6;

    stage(0, 0);
    __syncthreads();

    for (int t = 0; t < NT; ++t) {
        const int cur = t & 1;
        if (t + 1 < NT) stage(t + 1, cur ^ 1);

        const char* lb = lds + cur * BUF;
        bf16x8 aH[2][2], aL[2][2], bH[2][4], bL[2][4];
        #pragma unroll
        for (int s = 0; s < 2; ++s) {
            #pragma unroll
            for (int f = 0; f < 2; ++f) {
                aH[s][f] = *(const bf16x8*)(lb + aoff[f][s]);
                if constexpr (ALO) aL[s][f] = *(const bf16x8*)(lb + aoff[f][s] + 8192);
            }
            #pragma unroll
            for (int f = 0; f < 4; ++f) {
                bH[s][f] = *(const bf16x8*)(lb + boff[f][s]);
                bL[s][f] = *(const bf16x8*)(lb + boff[f][s] + 16384);
            }
        }
        #pragma unroll
        for (int s = 0; s < 2; ++s) {
            #pragma unroll
            for (int fm = 0; fm < 2; ++fm)
                #pragma unroll
                for (int fn = 0; fn < 4; ++fn)
                    acc[fm][fn] = __builtin_amdgcn_mfma_f32_16x16x32_bf16(
                        aH[s][fm], bH[s][fn], acc[fm][fn], 0, 0, 0);
            #pragma unroll
            for (int fm = 0; fm < 2; ++fm)
                #pragma unroll
                for (int fn = 0; fn < 4; ++fn)
                    acc[fm][fn] = __builtin_amdgcn_mfma_f32_16x16x32_bf16(
                        aH[s][fm], bL[s][fn], acc[fm][fn], 0, 0, 0);
            if constexpr (ALO) {
                #pragma unroll
                for (int fm = 0; fm < 2; ++fm)
                    #pragma unroll
                    for (int fn = 0; fn < 4; ++fn)
                        acc[fm][fn] = __builtin_amdgcn_mfma_f32_16x16x32_bf16(
                            aL[s][fm], bH[s][fn], acc[fm][fn], 0, 0, 0);
            }
        }
        __syncthreads();
    }

    #pragma unroll
    for (int fm = 0; fm < 2; ++fm) {
        #pragma unroll
        for (int fn = 0; fn < 4; ++fn) {
            const int col = bn + wn + fn * 16 + (lane & 15);
            const int rb  = bm + wm + fm * 16 + ((lane >> 4) << 2);
            if constexpr (PARTIAL) {
                #pragma unroll
                for (int r = 0; r < 4; ++r)
                    OF[(size_t)(kz * B_ROWS + rb + r) * N + col] = acc[fm][fn][r];
            } else {
                const float bc = bias[col];
                #pragma unroll
                for (int r = 0; r < 4; ++r) {
                    float v = acc[fm][fn][r] + bc;
                    v = v > 0.f ? v : 0.f;
                    float hf;
                    ushort hb = bf16_hi_bits(v, &hf);
                    Ohi[(size_t)(rb + r) * N + col] = hb;
                    Olo[(size_t)(rb + r) * N + col] = bf16_bits(v - hf);
                }
            }
        }
    }
}

// ---------------- mid/L6 GEMM (R5-proven): 128x128, wave 64x64, BK=64 --------
__global__ __launch_bounds__(256) void gemm_mid(
    const ushort* __restrict__ Ahi, const ushort* __restrict__ Alo,
    const ushort* __restrict__ Bhi, const ushort* __restrict__ Blo,
    float* __restrict__ OF, int N, int Kfull, int klen)
{
    constexpr int BUF = 65536;
    constexpr int OFF_A[2] = {0, 16384};
    constexpr int OFF_B[2] = {32768, 49152};
    __shared__ char lds[2 * BUF];

    const int tid = threadIdx.x, lane = tid & 63, wid = tid >> 6;

    const int gy = gridDim.y;
    const int nwg = gridDim.x * gy;
    int lin = blockIdx.x * gy + blockIdx.y;
    int q   = nwg >> 3;
    int sw  = (lin & 7) * q + (lin >> 3);
    int bx  = sw / gy, by2 = sw % gy;
    const int bm   = (by2 & 7) << 7;
    const int kz   = by2 >> 3;
    const int kbeg = kz * klen;
    const int bn   = bx << 7;

    const int wm = (wid >> 1) << 6;
    const int wn = (wid & 1) << 6;

    const int ch0 = (lane & 7) ^ (lane >> 3);
    const size_t kstep8 = (size_t)Kfull * 8;
    const ushort* gpb[4];
    uint lob[4];
    {
        const ushort* pls[4] = {Ahi, Alo, Bhi, Blo};
        const int row0s[4]   = {bm, bm, bn, bn};
        const uint bases[4]  = {OFF_A[0], OFF_A[1], OFF_B[0], OFF_B[1]};
        #pragma unroll
        for (int p = 0; p < 4; ++p) {
            gpb[p] = pls[p] + (size_t)(row0s[p] + wid * 32 + (lane >> 3)) * Kfull
                     + kbeg + ch0 * 8;
            lob[p] = bases[p] + wid * 4096;
        }
    }

    uint aoff[4][2], boff[4][2];
    #pragma unroll
    for (int f = 0; f < 4; ++f) {
        #pragma unroll
        for (int ks = 0; ks < 2; ++ks) {
            int ch = (ks * 4 + (lane >> 4)) ^ (lane & 7);
            aoff[f][ks] = OFF_A[0] + (wm + f * 16 + (lane & 15)) * 128 + ch * 16;
            boff[f][ks] = OFF_B[0] + (wn + f * 16 + (lane & 15)) * 128 + ch * 16;
        }
    }

    auto stage = [&](int kt, int b) {
        #pragma unroll
        for (int p = 0; p < 4; ++p)
            #pragma unroll
            for (int i = 0; i < 4; ++i)
                gload_lds16(gpb[p] + i * kstep8 + kt * 64,
                            lds + b * BUF + lob[p] + i * 1024);
    };

    f32x4 acc[4][4] = {};
    const int NT = klen >> 6;

    stage(0, 0);
    __syncthreads();

    for (int t = 0; t < NT; ++t) {
        const int cur = t & 1;
        if (t + 1 < NT) stage(t + 1, cur ^ 1);

        const char* lb = lds + cur * BUF;
        #pragma unroll
        for (int ks = 0; ks < 2; ++ks) {
            bf16x8 aH[4], aL[4], bH[4], bL[4];
            #pragma unroll
            for (int f = 0; f < 4; ++f) {
                aH[f] = *(const bf16x8*)(lb + aoff[f][ks]);
                aL[f] = *(const bf16x8*)(lb + aoff[f][ks] + 16384);
                bH[f] = *(const bf16x8*)(lb + boff[f][ks]);
                bL[f] = *(const bf16x8*)(lb + boff[f][ks] + 16384);
            }
            #pragma unroll
            for (int fm = 0; fm < 4; ++fm)
                #pragma unroll
                for (int fn = 0; fn < 4; ++fn)
                    acc[fm][fn] = __builtin_amdgcn_mfma_f32_16x16x32_bf16(
                        aH[fm], bH[fn], acc[fm][fn], 0, 0, 0);
            #pragma unroll
            for (int fm = 0; fm < 4; ++fm)
                #pragma unroll
                for (int fn = 0; fn < 4; ++fn)
                    acc[fm][fn] = __builtin_amdgcn_mfma_f32_16x16x32_bf16(
                        aH[fm], bL[fn], acc[fm][fn], 0, 0, 0);
            #pragma unroll
            for (int fm = 0; fm < 4; ++fm)
                #pragma unroll
                for (int fn = 0; fn < 4; ++fn)
                    acc[fm][fn] = __builtin_amdgcn_mfma_f32_16x16x32_bf16(
                        aL[fm], bH[fn], acc[fm][fn], 0, 0, 0);
        }
        __syncthreads();
    }

    #pragma unroll
    for (int fm = 0; fm < 4; ++fm) {
        #pragma unroll
        for (int fn = 0; fn < 4; ++fn) {
            const int col = bn + wn + fn * 16 + (lane & 15);
            const int rb  = bm + wm + fm * 16 + ((lane >> 4) << 2);
            #pragma unroll
            for (int r = 0; r < 4; ++r)
                OF[(size_t)(kz * B_ROWS + rb + r) * N + col] = acc[fm][fn][r];
        }
    }
}

// ---------------- mid combine: h = relu(p0+p1+bias) -> hi/lo planes ----------
__global__ __launch_bounds__(256) void combine_mid(
    const float* __restrict__ part, const float* __restrict__ bias,
    ushort* __restrict__ hi, ushort* __restrict__ lo)
{
    const int i = blockIdx.x * 256 + threadIdx.x;     // over 524288 float4
    const float4* p = (const float4*)part;
    float4 a = p[i], b = p[i + 524288];
    float4 bb = ((const float4*)bias)[i & 511];
    float f[4] = {a.x + b.x + bb.x, a.y + b.y + bb.y,
                  a.z + b.z + bb.z, a.w + b.w + bb.w};
    ushort hh[4], ll[4];
    #pragma unroll
    for (int c = 0; c < 4; ++c) {
        float v = f[c] > 0.f ? f[c] : 0.f;
        float hf;
        hh[c] = bf16_hi_bits(v, &hf);
        ll[c] = bf16_bits(v - hf);
    }
    ushort4 h4 = {hh[0], hh[1], hh[2], hh[3]};
    ushort4 l4 = {ll[0], ll[1], ll[2], ll[3]};
    reinterpret_cast<ushort4*>(hi)[i] = h4;
    reinterpret_cast<ushort4*>(lo)[i] = l4;
}

// ---------------- L6 combine: out = relu(sum_8 partial + bias) ---------------
__global__ __launch_bounds__(256) void combine_relu(
    const float* __restrict__ part, const float* __restrict__ bias,
    float* __restrict__ out)
{
    const int i = blockIdx.x * 256 + threadIdx.x;     // over 131072 float4
    const float4* p = (const float4*)part;
    float4 bb = ((const float4*)bias)[i & 127];
    float ox = bb.x, oy = bb.y, oz = bb.z, ow = bb.w;
    #pragma unroll
    for (int z = 0; z < 8; ++z) {
        float4 a = p[i + z * 131072];
        ox += a.x; oy += a.y; oz += a.z; ow += a.w;
    }
    float4 o;
    o.x = ox > 0.f ? ox : 0.f;
    o.y = oy > 0.f ? oy : 0.f;
    o.z = oz > 0.f ? oz : 0.f;
    o.w = ow > 0.f ? ow : 0.f;
    reinterpret_cast<float4*>(out)[i] = o;
}

// ---------------------------------------------------------------------------
extern "C" void kernel_launch(void* const* d_in, const int* in_sizes, int n_in,
                              void* d_out, int out_size, void* d_ws, size_t ws_size,
                              hipStream_t stream)
{
    const float* x     = (const float*)d_in[0];
    const float* emb_W = (const float*)d_in[1];
    const float* W_in  = (const float*)d_in[2];
    const float* b_in  = (const float*)d_in[3];
    const float* W_h   = (const float*)d_in[4];
    const float* b_h   = (const float*)d_in[5];
    const float* W_out = (const float*)d_in[6];
    const float* b_out = (const float*)d_in[7];
    float* out = (float*)d_out;

    char* w = (char*)d_ws;
    const size_t MB = 1 << 20;
    // phase-overlapped region [0..16MB)
    ushort* qhi    = (ushort*)(w);            // 1MB   (phase 1)
    ushort* wihi   = (ushort*)(w + 1*MB);     // 2MB   (phase 1)
    ushort* wilo   = (ushort*)(w + 3*MB);     // 2MB   (phase 1)
    float*  midpar = (float*)(w);             // 16MB  (phase 2: p0@0, p1@8MB)
    ushort* wohi   = (ushort*)(w);            // 2MB   (phase 3)
    ushort* wolo   = (ushort*)(w + 2*MB);     // 2MB   (phase 3)
    // persistent
    ushort* hhi    = (ushort*)(w + 16*MB);    // 4MB
    ushort* hlo    = (ushort*)(w + 20*MB);    // 4MB
    ushort* whhi   = (ushort*)(w + 24*MB);    // 8MB (dead after mids)
    ushort* whlo   = (ushort*)(w + 32*MB);    // 8MB (dead after mids)
    float*  l6par  = (float*)(w + 24*MB);     // 16MB (phase 3, reuses whh/whl)

    // 1) quantize (512 blocks, 4 elems/lane) + wi/wh split (1280 blocks)
    fused_pre<<<1792, 256, 0, stream>>>(x, emb_W, W_in, W_h,
                                        qhi, wihi, wilo, whhi, whlo, out + NTOT);

    // 2) L1: h = relu(q @ W_in^T + b_in)  M=1024 N=2048 K=512 (A exact, 2-term)
    gemm_split<false, false><<<dim3(16, 16), 256, 0, stream>>>(
        qhi, nullptr, wihi, wilo, b_in, hhi, hlo, nullptr, HDIM, D_IN, D_IN);

    // 3) 4x mid: partial = h @ W_h^T (splitK2, 256 blocks), combine -> h planes
    for (int l = 0; l < 4; ++l) {
        gemm_mid<<<dim3(16, 16), 256, 0, stream>>>(
            hhi, hlo, whhi, whlo, midpar, HDIM, HDIM, 1024);
        combine_mid<<<2048, 256, 0, stream>>>(midpar, b_h, hhi, hlo);
    }

    // 4) split W_out into freed phase-3 region
    wo_split<<<256, 256, 0, stream>>>(W_out, wohi, wolo);

    // 5) L6: partial = h @ W_out^T (splitK8, 256 blocks)  M=1024 N=512 K=2048
    gemm_mid<<<dim3(4, 64), 256, 0, stream>>>(
        hhi, hlo, wohi, wolo, l6par, D_IN, HDIM, 256);

    // 6) combine 8 partials + bias + relu -> d_out
    combine_relu<<<512, 256, 0, stream>>>(l6par, b_out, out);
}

// Round 12
// 213.378 us; speedup vs baseline: 1.0220x; 1.0220x over previous
//
#include <hip/hip_runtime.h>
#include <hip/hip_bf16.h>
#include <math.h>

// ---------------------------------------------------------------------------
// VQ quantizer + 6-layer ReLU MLP via split-bf16 MFMA.
//   f32 GEMM ~= Ah*Bh + Ah*Bl + Al*Bh  (drop lo*lo ~2^-16 rel)
//   R12: R10 base (212.2us) + fused_pre v4: packed-f32 over CODE pairs via
//        __builtin_elementwise_fma on f32x2 (compiler-scheduled v_pk_fma_f32,
//        no asm), pair-interleaved codebook rows (4x b128 + 1x b64 per pair).
//        E=2 elems/lane, 1024 blocks (proven occupancy). Distance bits and
//        first-index-wins order identical to R10.
// Workspace map (40MB):
//   [0..16M)  phase1: qhi@0(1M), wihi@1M, wilo@3M   (dead after L1)
//             phase2: mid partial p0@0(8M), p1@8M
//             phase3: wohi@0(2M), wolo@2M
//   [16..24M) h planes: hhi@16M, hlo@20M
//   [24..40M) whhi@24M, whlo@32M (dead after mids) -> phase3: l6par@24M(16M)
// ---------------------------------------------------------------------------

#define B_ROWS 1024
#define D_IN   512
#define HDIM   2048
#define NTOT   (B_ROWS * D_IN)
#define NCODE  256
#define EDIM   8

typedef __attribute__((ext_vector_type(8))) short bf16x8;
typedef __attribute__((ext_vector_type(4))) float f32x4;
typedef __attribute__((ext_vector_type(2))) float f32x2;

__device__ inline void gload_lds16(const void* g, void* l) {
    __builtin_amdgcn_global_load_lds(
        (const __attribute__((address_space(1))) void*)g,
        (__attribute__((address_space(3))) void*)l, 16, 0, 0);
}

__device__ inline ushort bf16_hi_bits(float v, float* hi_f) {
    __hip_bfloat16 h = __float2bfloat16(v);
    *hi_f = __bfloat162float(h);
    ushort u; __builtin_memcpy(&u, &h, 2); return u;
}
__device__ inline ushort bf16_bits(float v) {
    __hip_bfloat16 h = __float2bfloat16(v);
    ushort u; __builtin_memcpy(&u, &h, 2); return u;
}

// ---------------- fused: quantize (blocks 0..1023) + wi/wh split -------------
// Quantize v4: code-pair packed f32. Per-code distance bits identical to R10:
//   dot = fma-chain(p2[e]*w[e]) starting RN(p2[0]*w[0]); d = RN(RN(sm+E)-dot).
//   (v_pk_* per-lane == scalar RN ops; +/-0 differences cannot affect <.)
__global__ __launch_bounds__(256) void fused_pre(
    const float* __restrict__ x, const float* __restrict__ embW,
    const float* __restrict__ Wi, const float* __restrict__ Wh,
    ushort* __restrict__ qhi,
    ushort* __restrict__ wihi, ushort* __restrict__ wilo,
    ushort* __restrict__ whhi, ushort* __restrict__ whlo,
    float* __restrict__ loss_out)
{
    __shared__ float sP[NCODE / 2][20];  // 80B rows: pair-interleaved w + E pair
    const int tid = threadIdx.x;

    if (blockIdx.x >= 1024) {
        // ---- weight split: 1280 blocks x 256 thr x 4 float4 ----
        const int sidx = blockIdx.x - 1024;
        #pragma unroll
        for (int s = 0; s < 4; ++s) {
            const int g = sidx * 1024 + s * 256 + tid;   // < 1310720
            const float* src; ushort* hi; ushort* lo; int j;
            if (g < 262144) { src = Wi; hi = wihi; lo = wilo; j = g; }
            else            { src = Wh; hi = whhi; lo = whlo; j = g - 262144; }
            float4 v = reinterpret_cast<const float4*>(src)[j];
            float f[4] = {v.x, v.y, v.z, v.w};
            ushort hh[4], ll[4];
            #pragma unroll
            for (int c = 0; c < 4; ++c) {
                float hf;
                hh[c] = bf16_hi_bits(f[c], &hf);
                ll[c] = bf16_bits(f[c] - hf);
            }
            ushort4 h4 = {hh[0], hh[1], hh[2], hh[3]};
            ushort4 l4 = {ll[0], ll[1], ll[2], ll[3]};
            reinterpret_cast<ushort4*>(hi)[j] = h4;
            reinterpret_cast<ushort4*>(lo)[j] = l4;
        }
        return;
    }

    // ---- build pair-interleaved codebook rows (threads 0..127) ----
    if (tid < NCODE / 2) {
        const float4 a0 = *reinterpret_cast<const float4*>(&embW[(2 * tid) * EDIM]);
        const float4 b0 = *reinterpret_cast<const float4*>(&embW[(2 * tid) * EDIM + 4]);
        const float4 a1 = *reinterpret_cast<const float4*>(&embW[(2 * tid + 1) * EDIM]);
        const float4 b1 = *reinterpret_cast<const float4*>(&embW[(2 * tid + 1) * EDIM + 4]);
        // E (numpy pairwise order, same bits as all passing rounds)
        float E0, E1;
        {
            float s0 = __fmul_rn(a0.x, a0.x), s1 = __fmul_rn(a0.y, a0.y);
            float s2 = __fmul_rn(a0.z, a0.z), s3 = __fmul_rn(a0.w, a0.w);
            float s4 = __fmul_rn(b0.x, b0.x), s5 = __fmul_rn(b0.y, b0.y);
            float s6 = __fmul_rn(b0.z, b0.z), s7 = __fmul_rn(b0.w, b0.w);
            float a = __fadd_rn(__fadd_rn(s0, s1), __fadd_rn(s2, s3));
            float b = __fadd_rn(__fadd_rn(s4, s5), __fadd_rn(s6, s7));
            E0 = __fadd_rn(a, b);
        }
        {
            float s0 = __fmul_rn(a1.x, a1.x), s1 = __fmul_rn(a1.y, a1.y);
            float s2 = __fmul_rn(a1.z, a1.z), s3 = __fmul_rn(a1.w, a1.w);
            float s4 = __fmul_rn(b1.x, b1.x), s5 = __fmul_rn(b1.y, b1.y);
            float s6 = __fmul_rn(b1.z, b1.z), s7 = __fmul_rn(b1.w, b1.w);
            float a = __fadd_rn(__fadd_rn(s0, s1), __fadd_rn(s2, s3));
            float b = __fadd_rn(__fadd_rn(s4, s5), __fadd_rn(s6, s7));
            E1 = __fadd_rn(a, b);
        }
        float* r = sP[tid];
        r[0]  = a0.x; r[1]  = a1.x; r[2]  = a0.y; r[3]  = a1.y;
        r[4]  = a0.z; r[5]  = a1.z; r[6]  = a0.w; r[7]  = a1.w;
        r[8]  = b0.x; r[9]  = b1.x; r[10] = b0.y; r[11] = b1.y;
        r[12] = b0.z; r[13] = b1.z; r[14] = b0.w; r[15] = b1.w;
        r[16] = E0;   r[17] = E1;
    }
    __syncthreads();

    const int nbase = blockIdx.x * 512 + tid;      // elems nbase, nbase+256

    float p2[2][EDIM], sm[2];
    #pragma unroll
    for (int j = 0; j < 2; ++j) {
        const float v = x[nbase + j * 256];
        float p[EDIM];
        #pragma unroll
        for (int e = 0; e < EDIM; ++e)
            p[e] = powf(v, (float)(e + 1));        // match np.power f32
        float a = __fadd_rn(__fadd_rn(p[0], p[1]), __fadd_rn(p[2], p[3]));
        float b = __fadd_rn(__fadd_rn(p[4], p[5]), __fadd_rn(p[6], p[7]));
        sm[j] = __fadd_rn(a, b);
        #pragma unroll
        for (int e = 0; e < EDIM; ++e)
            p2[j][e] = 2.0f * p[e];                // exact pow2 fold
    }

    // duplicated pairs for pk lanes
    f32x2 p2b[2][EDIM], smb[2];
    #pragma unroll
    for (int j = 0; j < 2; ++j) {
        #pragma unroll
        for (int e = 0; e < EDIM; ++e) { p2b[j][e][0] = p2[j][e]; p2b[j][e][1] = p2[j][e]; }
        smb[j][0] = sm[j]; smb[j][1] = sm[j];
    }

    float best[2] = {INFINITY, INFINITY};
    int   bi[2]   = {0, 0};

    #pragma unroll 2
    for (int kk = 0; kk < NCODE / 2; ++kk) {
        const float* r = sP[kk];
        const f32x4 c0 = *reinterpret_cast<const f32x4*>(r);       // e0,e1 pairs
        const f32x4 c1 = *reinterpret_cast<const f32x4*>(r + 4);   // e2,e3
        const f32x4 c2 = *reinterpret_cast<const f32x4*>(r + 8);   // e4,e5
        const f32x4 c3 = *reinterpret_cast<const f32x4*>(r + 12);  // e6,e7
        const f32x2 ep = *reinterpret_cast<const f32x2*>(r + 16);  // E pair

        const f32x2 w0 = __builtin_shufflevector(c0, c0, 0, 1);
        const f32x2 w1 = __builtin_shufflevector(c0, c0, 2, 3);
        const f32x2 w2 = __builtin_shufflevector(c1, c1, 0, 1);
        const f32x2 w3 = __builtin_shufflevector(c1, c1, 2, 3);
        const f32x2 w4 = __builtin_shufflevector(c2, c2, 0, 1);
        const f32x2 w5 = __builtin_shufflevector(c2, c2, 2, 3);
        const f32x2 w6 = __builtin_shufflevector(c3, c3, 0, 1);
        const f32x2 w7 = __builtin_shufflevector(c3, c3, 2, 3);

        #pragma unroll
        for (int j = 0; j < 2; ++j) {
            f32x2 dot = p2b[j][0] * w0;            // RN mul (== fma(..,0) chain head)
            dot = __builtin_elementwise_fma(p2b[j][1], w1, dot);
            dot = __builtin_elementwise_fma(p2b[j][2], w2, dot);
            dot = __builtin_elementwise_fma(p2b[j][3], w3, dot);
            dot = __builtin_elementwise_fma(p2b[j][4], w4, dot);
            dot = __builtin_elementwise_fma(p2b[j][5], w5, dot);
            dot = __builtin_elementwise_fma(p2b[j][6], w6, dot);
            dot = __builtin_elementwise_fma(p2b[j][7], w7, dot);
            f32x2 smek = smb[j] + ep;              // RN add
            f32x2 d    = smek - dot;               // RN sub
            // first-index-wins: code 2kk before 2kk+1
            if (d[0] < best[j]) { best[j] = d[0]; bi[j] = 2 * kk; }
            if (d[1] < best[j]) { best[j] = d[1]; bi[j] = 2 * kk + 1; }
        }
    }

    #pragma unroll
    for (int j = 0; j < 2; ++j) {
        const int n  = nbase + j * 256;
        const int bo = n & (B_ROWS - 1);
        const int dd = n >> 10;
        qhi[bo * D_IN + dd] = bf16_bits((float)bi[j]);     // 0..255 exact bf16
    }
    if (blockIdx.x == 0 && tid == 0) loss_out[0] = 0.0f;
}

// ---------------- wo split (after mids; writes into freed phase-3 region) ----
__global__ __launch_bounds__(256) void wo_split(
    const float* __restrict__ Wo, ushort* __restrict__ hi, ushort* __restrict__ lo)
{
    const int tid = threadIdx.x;
    #pragma unroll
    for (int s = 0; s < 4; ++s) {
        const int j = blockIdx.x * 1024 + s * 256 + tid;   // < 262144
        float4 v = reinterpret_cast<const float4*>(Wo)[j];
        float f[4] = {v.x, v.y, v.z, v.w};
        ushort hh[4], ll[4];
        #pragma unroll
        for (int c = 0; c < 4; ++c) {
            float hf;
            hh[c] = bf16_hi_bits(f[c], &hf);
            ll[c] = bf16_bits(f[c] - hf);
        }
        ushort4 h4 = {hh[0], hh[1], hh[2], hh[3]};
        ushort4 l4 = {ll[0], ll[1], ll[2], ll[3]};
        reinterpret_cast<ushort4*>(hi)[j] = h4;
        reinterpret_cast<ushort4*>(lo)[j] = l4;
    }
}

// ---------------- L1 GEMM (R3-proven): block 64x128, wave 32x64, BK=64 -------
template<bool ALO, bool PARTIAL>
__global__ __launch_bounds__(256) void gemm_split(
    const ushort* __restrict__ Ahi, const ushort* __restrict__ Alo,
    const ushort* __restrict__ Whi, const ushort* __restrict__ Wlo,
    const float* __restrict__ bias,
    ushort* __restrict__ Ohi, ushort* __restrict__ Olo,
    float* __restrict__ OF, int N, int K, int klen)
{
    constexpr int BUF = 49152;
    constexpr int OFF_AH = 0, OFF_AL = 8192, OFF_BH = 16384;
    __shared__ char lds[2 * BUF];

    const int tid = threadIdx.x, lane = tid & 63, wid = tid >> 6;

    const int gy = gridDim.y;
    const int nwg = gridDim.x * gy;
    int lin = blockIdx.x * gy + blockIdx.y;
    int q   = nwg >> 3;
    int sw  = (lin & 7) * q + (lin >> 3);
    int bx  = sw / gy, by2 = sw % gy;
    const int bm   = (by2 & 15) << 6;
    const int kz   = by2 >> 4;
    const int kbeg = kz * klen;
    const int bn   = bx << 7;

    const int wm = (wid >> 1) << 5;
    const int wn = (wid & 1) << 6;

    constexpr int NSEGW = ALO ? 12 : 10;
    const ushort* gp[NSEGW];
    uint ldsoff[NSEGW];
    #pragma unroll
    for (int i = 0; i < NSEGW; ++i) {
        int s = wid + i * 4;
        const ushort* pl; int row0, base, sip;
        if (ALO) {
            if (s < 8)       { pl = Ahi; row0 = bm; base = OFF_AH;         sip = s; }
            else if (s < 16) { pl = Alo; row0 = bm; base = OFF_AL;         sip = s - 8; }
            else if (s < 32) { pl = Whi; row0 = bn; base = OFF_BH;         sip = s - 16; }
            else             { pl = Wlo; row0 = bn; base = OFF_BH + 16384; sip = s - 32; }
        } else {
            if (s < 8)       { pl = Ahi; row0 = bm; base = OFF_AH;         sip = s; }
            else if (s < 24) { pl = Whi; row0 = bn; base = OFF_BH;         sip = s - 8; }
            else             { pl = Wlo; row0 = bn; base = OFF_BH + 16384; sip = s - 24; }
        }
        int r  = sip * 8 + (lane >> 3);
        int ch = (lane & 7) ^ (r & 7);
        gp[i]     = pl + (size_t)(row0 + r) * K + kbeg + ch * 8;
        ldsoff[i] = base + sip * 1024;
    }

    uint aoff[2][2], boff[4][2];
    #pragma unroll
    for (int f = 0; f < 2; ++f) {
        int ar = wm + f * 16 + (lane & 15);
        #pragma unroll
        for (int s = 0; s < 2; ++s) {
            int ch = (s * 4 + (lane >> 4)) ^ (ar & 7);
            aoff[f][s] = OFF_AH + ar * 128 + ch * 16;
        }
    }
    #pragma unroll
    for (int f = 0; f < 4; ++f) {
        int br = wn + f * 16 + (lane & 15);
        #pragma unroll
        for (int s = 0; s < 2; ++s) {
            int ch = (s * 4 + (lane >> 4)) ^ (br & 7);
            boff[f][s] = OFF_BH + br * 128 + ch * 16;
        }
    }

    auto stage = [&](int kt, int b) {
        #pragma unroll
        for (int i = 0; i < NSEGW; ++i)
            gload_lds16(gp[i] + kt * 64, lds + b * BUF + ldsoff[i]);
    };

    f32x4 acc[2][4] = {};
    const int NT = klen >> 6;

    stage(0, 0);
    __syncthreads();

    for (int t = 0; t < NT; ++t) {
        const int cur = t & 1;
        if (t + 1 < NT) stage(t + 1, cur ^ 1);

        const char* lb = lds + cur * BUF;
        bf16x8 aH[2][2], aL[2][2], bH[2][4], bL[2][4];
        #pragma unroll
        for (int s = 0; s < 2; ++s) {
            #pragma unroll
            for (int f = 0; f < 2; ++f) {
                aH[s][f] = *(const bf16x8*)(lb + aoff[f][s]);
                if constexpr (ALO) aL[s][f] = *(const bf16x8*)(lb + aoff[f][s] + 8192);
            }
            #pragma unroll
            for (int f = 0; f < 4; ++f) {
                bH[s][f] = *(const bf16x8*)(lb + boff[f][s]);
                bL[s][f] = *(const bf16x8*)(lb + boff[f][s] + 16384);
            }
        }
        #pragma unroll
        for (int s = 0; s < 2; ++s) {
            #pragma unroll
            for (int fm = 0; fm < 2; ++fm)
                #pragma unroll
                for (int fn = 0; fn < 4; ++fn)
                    acc[fm][fn] = __builtin_amdgcn_mfma_f32_16x16x32_bf16(
                        aH[s][fm], bH[s][fn], acc[fm][fn], 0, 0, 0);
            #pragma unroll
            for (int fm = 0; fm < 2; ++fm)
                #pragma unroll
                for (int fn = 0; fn < 4; ++fn)
                    acc[fm][fn] = __builtin_amdgcn_mfma_f32_16x16x32_bf16(
                        aH[s][fm], bL[s][fn], acc[fm][fn], 0, 0, 0);
            if constexpr (ALO) {
                #pragma unroll
                for (int fm = 0; fm < 2; ++fm)
                    #pragma unroll
                    for (int fn = 0; fn < 4; ++fn)
                        acc[fm][fn] = __builtin_amdgcn_mfma_f32_16x16x32_bf16(
                            aL[s][fm], bH[s][fn], acc[fm][fn], 0, 0, 0);
            }
        }
        __syncthreads();
    }

    #pragma unroll
    for (int fm = 0; fm < 2; ++fm) {
        #pragma unroll
        for (int fn = 0; fn < 4; ++fn) {
            const int col = bn + wn + fn * 16 + (lane & 15);
            const int rb  = bm + wm + fm * 16 + ((lane >> 4) << 2);
            if constexpr (PARTIAL) {
                #pragma unroll
                for (int r = 0; r < 4; ++r)
                    OF[(size_t)(kz * B_ROWS + rb + r) * N + col] = acc[fm][fn][r];
            } else {
                const float bc = bias[col];
                #pragma unroll
                for (int r = 0; r < 4; ++r) {
                    float v = acc[fm][fn][r] + bc;
                    v = v > 0.f ? v : 0.f;
                    float hf;
                    ushort hb = bf16_hi_bits(v, &hf);
                    Ohi[(size_t)(rb + r) * N + col] = hb;
                    Olo[(size_t)(rb + r) * N + col] = bf16_bits(v - hf);
                }
            }
        }
    }
}

// ---------------- mid/L6 GEMM (R5-proven): 128x128, wave 64x64, BK=64 --------
__global__ __launch_bounds__(256) void gemm_mid(
    const ushort* __restrict__ Ahi, const ushort* __restrict__ Alo,
    const ushort* __restrict__ Bhi, const ushort* __restrict__ Blo,
    float* __restrict__ OF, int N, int Kfull, int klen)
{
    constexpr int BUF = 65536;
    constexpr int OFF_A[2] = {0, 16384};
    constexpr int OFF_B[2] = {32768, 49152};
    __shared__ char lds[2 * BUF];

    const int tid = threadIdx.x, lane = tid & 63, wid = tid >> 6;

    const int gy = gridDim.y;
    const int nwg = gridDim.x * gy;
    int lin = blockIdx.x * gy + blockIdx.y;
    int q   = nwg >> 3;
    int sw  = (lin & 7) * q + (lin >> 3);
    int bx  = sw / gy, by2 = sw % gy;
    const int bm   = (by2 & 7) << 7;
    const int kz   = by2 >> 3;
    const int kbeg = kz * klen;
    const int bn   = bx << 7;

    const int wm = (wid >> 1) << 6;
    const int wn = (wid & 1) << 6;

    const int ch0 = (lane & 7) ^ (lane >> 3);
    const size_t kstep8 = (size_t)Kfull * 8;
    const ushort* gpb[4];
    uint lob[4];
    {
        const ushort* pls[4] = {Ahi, Alo, Bhi, Blo};
        const int row0s[4]   = {bm, bm, bn, bn};
        const uint bases[4]  = {OFF_A[0], OFF_A[1], OFF_B[0], OFF_B[1]};
        #pragma unroll
        for (int p = 0; p < 4; ++p) {
            gpb[p] = pls[p] + (size_t)(row0s[p] + wid * 32 + (lane >> 3)) * Kfull
                     + kbeg + ch0 * 8;
            lob[p] = bases[p] + wid * 4096;
        }
    }

    uint aoff[4][2], boff[4][2];
    #pragma unroll
    for (int f = 0; f < 4; ++f) {
        #pragma unroll
        for (int ks = 0; ks < 2; ++ks) {
            int ch = (ks * 4 + (lane >> 4)) ^ (lane & 7);
            aoff[f][ks] = OFF_A[0] + (wm + f * 16 + (lane & 15)) * 128 + ch * 16;
            boff[f][ks] = OFF_B[0] + (wn + f * 16 + (lane & 15)) * 128 + ch * 16;
        }
    }

    auto stage = [&](int kt, int b) {
        #pragma unroll
        for (int p = 0; p < 4; ++p)
            #pragma unroll
            for (int i = 0; i < 4; ++i)
                gload_lds16(gpb[p] + i * kstep8 + kt * 64,
                            lds + b * BUF + lob[p] + i * 1024);
    };

    f32x4 acc[4][4] = {};
    const int NT = klen >> 6;

    stage(0, 0);
    __syncthreads();

    for (int t = 0; t < NT; ++t) {
        const int cur = t & 1;
        if (t + 1 < NT) stage(t + 1, cur ^ 1);

        const char* lb = lds + cur * BUF;
        #pragma unroll
        for (int ks = 0; ks < 2; ++ks) {
            bf16x8 aH[4], aL[4], bH[4], bL[4];
            #pragma unroll
            for (int f = 0; f < 4; ++f) {
                aH[f] = *(const bf16x8*)(lb + aoff[f][ks]);
                aL[f] = *(const bf16x8*)(lb + aoff[f][ks] + 16384);
                bH[f] = *(const bf16x8*)(lb + boff[f][ks]);
                bL[f] = *(const bf16x8*)(lb + boff[f][ks] + 16384);
            }
            #pragma unroll
            for (int fm = 0; fm < 4; ++fm)
                #pragma unroll
                for (int fn = 0; fn < 4; ++fn)
                    acc[fm][fn] = __builtin_amdgcn_mfma_f32_16x16x32_bf16(
                        aH[fm], bH[fn], acc[fm][fn], 0, 0, 0);
            #pragma unroll
            for (int fm = 0; fm < 4; ++fm)
                #pragma unroll
                for (int fn = 0; fn < 4; ++fn)
                    acc[fm][fn] = __builtin_amdgcn_mfma_f32_16x16x32_bf16(
                        aH[fm], bL[fn], acc[fm][fn], 0, 0, 0);
            #pragma unroll
            for (int fm = 0; fm < 4; ++fm)
                #pragma unroll
                for (int fn = 0; fn < 4; ++fn)
                    acc[fm][fn] = __builtin_amdgcn_mfma_f32_16x16x32_bf16(
                        aL[fm], bH[fn], acc[fm][fn], 0, 0, 0);
        }
        __syncthreads();
    }

    #pragma unroll
    for (int fm = 0; fm < 4; ++fm) {
        #pragma unroll
        for (int fn = 0; fn < 4; ++fn) {
            const int col = bn + wn + fn * 16 + (lane & 15);
            const int rb  = bm + wm + fm * 16 + ((lane >> 4) << 2);
            #pragma unroll
            for (int r = 0; r < 4; ++r)
                OF[(size_t)(kz * B_ROWS + rb + r) * N + col] = acc[fm][fn][r];
        }
    }
}

// ---------------- mid combine: h = relu(p0+p1+bias) -> hi/lo planes ----------
__global__ __launch_bounds__(256) void combine_mid(
    const float* __restrict__ part, const float* __restrict__ bias,
    ushort* __restrict__ hi, ushort* __restrict__ lo)
{
    const int i = blockIdx.x * 256 + threadIdx.x;     // over 524288 float4
    const float4* p = (const float4*)part;
    float4 a = p[i], b = p[i + 524288];
    float4 bb = ((const float4*)bias)[i & 511];
    float f[4] = {a.x + b.x + bb.x, a.y + b.y + bb.y,
                  a.z + b.z + bb.z, a.w + b.w + bb.w};
    ushort hh[4], ll[4];
    #pragma unroll
    for (int c = 0; c < 4; ++c) {
        float v = f[c] > 0.f ? f[c] : 0.f;
        float hf;
        hh[c] = bf16_hi_bits(v, &hf);
        ll[c] = bf16_bits(v - hf);
    }
    ushort4 h4 = {hh[0], hh[1], hh[2], hh[3]};
    ushort4 l4 = {ll[0], ll[1], ll[2], ll[3]};
    reinterpret_cast<ushort4*>(hi)[i] = h4;
    reinterpret_cast<ushort4*>(lo)[i] = l4;
}

// ---------------- L6 combine: out = relu(sum_8 partial + bias) ---------------
__global__ __launch_bounds__(256) void combine_relu(
    const float* __restrict__ part, const float* __restrict__ bias,
    float* __restrict__ out)
{
    const int i = blockIdx.x * 256 + threadIdx.x;     // over 131072 float4
    const float4* p = (const float4*)part;
    float4 bb = ((const float4*)bias)[i & 127];
    float ox = bb.x, oy = bb.y, oz = bb.z, ow = bb.w;
    #pragma unroll
    for (int z = 0; z < 8; ++z) {
        float4 a = p[i + z * 131072];
        ox += a.x; oy += a.y; oz += a.z; ow += a.w;
    }
    float4 o;
    o.x = ox > 0.f ? ox : 0.f;
    o.y = oy > 0.f ? oy : 0.f;
    o.z = oz > 0.f ? oz : 0.f;
    o.w = ow > 0.f ? ow : 0.f;
    reinterpret_cast<float4*>(out)[i] = o;
}

// ---------------------------------------------------------------------------
extern "C" void kernel_launch(void* const* d_in, const int* in_sizes, int n_in,
                              void* d_out, int out_size, void* d_ws, size_t ws_size,
                              hipStream_t stream)
{
    const float* x     = (const float*)d_in[0];
    const float* emb_W = (const float*)d_in[1];
    const float* W_in  = (const float*)d_in[2];
    const float* b_in  = (const float*)d_in[3];
    const float* W_h   = (const float*)d_in[4];
    const float* b_h   = (const float*)d_in[5];
    const float* W_out = (const float*)d_in[6];
    const float* b_out = (const float*)d_in[7];
    float* out = (float*)d_out;

    char* w = (char*)d_ws;
    const size_t MB = 1 << 20;
    // phase-overlapped region [0..16MB)
    ushort* qhi    = (ushort*)(w);            // 1MB   (phase 1)
    ushort* wihi   = (ushort*)(w + 1*MB);     // 2MB   (phase 1)
    ushort* wilo   = (ushort*)(w + 3*MB);     // 2MB   (phase 1)
    float*  midpar = (float*)(w);             // 16MB  (phase 2: p0@0, p1@8MB)
    ushort* wohi   = (ushort*)(w);            // 2MB   (phase 3)
    ushort* wolo   = (ushort*)(w + 2*MB);     // 2MB   (phase 3)
    // persistent
    ushort* hhi    = (ushort*)(w + 16*MB);    // 4MB
    ushort* hlo    = (ushort*)(w + 20*MB);    // 4MB
    ushort* whhi   = (ushort*)(w + 24*MB);    // 8MB (dead after mids)
    ushort* whlo   = (ushort*)(w + 32*MB);    // 8MB (dead after mids)
    float*  l6par  = (float*)(w + 24*MB);     // 16MB (phase 3, reuses whh/whl)

    // 1) quantize + wi/wh split (fused); writes loss scalar at out[NTOT]
    fused_pre<<<2304, 256, 0, stream>>>(x, emb_W, W_in, W_h,
                                        qhi, wihi, wilo, whhi, whlo, out + NTOT);

    // 2) L1: h = relu(q @ W_in^T + b_in)  M=1024 N=2048 K=512 (A exact, 2-term)
    gemm_split<false, false><<<dim3(16, 16), 256, 0, stream>>>(
        qhi, nullptr, wihi, wilo, b_in, hhi, hlo, nullptr, HDIM, D_IN, D_IN);

    // 3) 4x mid: partial = h @ W_h^T (splitK2, 256 blocks), combine -> h planes
    for (int l = 0; l < 4; ++l) {
        gemm_mid<<<dim3(16, 16), 256, 0, stream>>>(
            hhi, hlo, whhi, whlo, midpar, HDIM, HDIM, 1024);
        combine_mid<<<2048, 256, 0, stream>>>(midpar, b_h, hhi, hlo);
    }

    // 4) split W_out into freed phase-3 region
    wo_split<<<256, 256, 0, stream>>>(W_out, wohi, wolo);

    // 5) L6: partial = h @ W_out^T (splitK8, 256 blocks)  M=1024 N=512 K=2048
    gemm_mid<<<dim3(4, 64), 256, 0, stream>>>(
        hhi, hlo, wohi, wolo, l6par, D_IN, HDIM, 256);

    // 6) combine 8 partials + bias + relu -> d_out
    combine_relu<<<512, 256, 0, stream>>>(l6par, b_out, out);
}